// Round 3
// baseline (196.179 us; speedup 1.0000x reference)
//
#include <hip/hip_runtime.h>

#define HW 32
#define NPIX 1024      // 32*32
#define IMG 3072       // 3*32*32

// ---------------- threefry2x32 (JAX partitionable semantics) ----------------
__device__ __forceinline__ unsigned rotl32(unsigned x, int d) {
    return (x << d) | (x >> (32 - d));
}

struct UPair { unsigned a, b; };

__device__ __forceinline__ UPair threefry2x32(unsigned k0, unsigned k1,
                                              unsigned x0, unsigned x1) {
    unsigned k2 = k0 ^ k1 ^ 0x1BD11BDAu;
    x0 += k0; x1 += k1;
#define RND(r) { x0 += x1; x1 = rotl32(x1, (r)); x1 ^= x0; }
    RND(13) RND(15) RND(26) RND(6)
    x0 += k1; x1 += k2 + 1u;
    RND(17) RND(29) RND(16) RND(24)
    x0 += k2; x1 += k0 + 2u;
    RND(13) RND(15) RND(26) RND(6)
    x0 += k0; x1 += k1 + 3u;
    RND(17) RND(29) RND(16) RND(24)
    x0 += k1; x1 += k2 + 4u;
    RND(13) RND(15) RND(26) RND(6)
    x0 += k2; x1 += k0 + 5u;
#undef RND
    return {x0, x1};
}

__device__ __forceinline__ float bits_to_u01(unsigned bits) {
    return __uint_as_float((bits >> 9) | 0x3f800000u) - 1.0f;
}

// reference _reflect, lo=-0.5 span=32, manual fmod (args are small & positive)
__device__ __forceinline__ float reflect32(float c) {
    float t = fabsf(c + 0.5f);
    float f = floorf(t * 0.03125f);
    float extra = t - 32.0f * f;
    float par = f - 2.0f * floorf(f * 0.5f);   // 0 or 1
    float o = (par == 0.0f) ? (extra - 0.5f) : (31.5f - extra);
    return fminf(fmaxf(o, 0.0f), 31.0f);
}

__global__ __launch_bounds__(256) void aug_kernel(
    const float* __restrict__ xin, const float* __restrict__ aff,
    const int* __restrict__ apply_crop, float* __restrict__ out, int B) {
    __shared__ __align__(16) float bufA[IMG];
    __shared__ __align__(16) float bufB[IMG];
    __shared__ float s_theta[6];
    __shared__ int s_top, s_left, s_flip, s_hue, s_gray, s_blur, s_solar;
    __shared__ float s_bright, s_contr, s_sat;

    const int b = blockIdx.x;
    const int t = threadIdx.x;
    const bool do_crop = (apply_crop[0] != 0);

    const float MEANc[3] = {0.5071f, 0.4867f, 0.4408f};
    const float STDc[3]  = {0.2675f, 0.2565f, 0.2761f};
    const float INVSTD[3] = {1.0f / 0.2675f, 1.0f / 0.2565f, 1.0f / 0.2761f};

    // ---- issue global image loads early (4 consecutive px per channel) ----
    const float* imgp = xin + (size_t)b * IMG;
    const int p0 = 4 * t;
    float4 g0 = *(const float4*)(imgp + p0);
    float4 g1 = *(const float4*)(imgp + NPIX + p0);
    float4 g2 = *(const float4*)(imgp + 2 * NPIX + p0);

    const size_t OUT_IMG = (size_t)B * IMG;
    if (t < 6) {  // theta into LDS + affine passthrough output
        float v = aff[b * 6 + t];
        s_theta[t] = v;
        out[OUT_IMG + (size_t)B + (size_t)b * 6 + t] = v;
    }

    // ---- per-image RNG (jax_threefry_partitionable=True) ----
    if (t < 10) {
        int k = t;
        UPair K = threefry2x32(0u, 42u, 0u, (unsigned)k);  // ks[k]
        if (k < 2) {
            UPair k2 = threefry2x32(K.a, K.b, 0u, 1u);
            UPair r = threefry2x32(k2.a, k2.b, 0u, (unsigned)b);
            int val = (int)((r.a ^ r.b) & 7u);
            if (k == 0) s_top = val; else s_left = val;
        } else {
            UPair r = threefry2x32(K.a, K.b, 0u, (unsigned)b);
            float u = bits_to_u01(r.a ^ r.b);
            if      (k == 2) s_flip  = (u < 0.5f);
            else if (k == 3) s_bright = 1.0f + (u - 0.5f) * 0.8f;
            else if (k == 4) s_contr  = 1.0f + (u - 0.5f) * 0.8f;
            else if (k == 5) s_sat    = 1.0f + (u - 0.5f) * 0.8f;
            else if (k == 6) s_hue   = (u < 0.5f);
            else if (k == 7) s_gray  = (u < 0.2f);
            else if (k == 8) s_blur  = (u < 0.5f);
            else             s_solar = (u < 0.1f);
        }
    }

    // ---- denormalize + stage planar into LDS (contiguous b128 writes) ----
    {
        float4 v = g0;
        v.x = v.x * STDc[0] + MEANc[0]; v.y = v.y * STDc[0] + MEANc[0];
        v.z = v.z * STDc[0] + MEANc[0]; v.w = v.w * STDc[0] + MEANc[0];
        *(float4*)(bufA + p0) = v;
        v = g1;
        v.x = v.x * STDc[1] + MEANc[1]; v.y = v.y * STDc[1] + MEANc[1];
        v.z = v.z * STDc[1] + MEANc[1]; v.w = v.w * STDc[1] + MEANc[1];
        *(float4*)(bufA + NPIX + p0) = v;
        v = g2;
        v.x = v.x * STDc[2] + MEANc[2]; v.y = v.y * STDc[2] + MEANc[2];
        v.z = v.z * STDc[2] + MEANc[2]; v.w = v.w * STDc[2] + MEANc[2];
        *(float4*)(bufA + 2 * NPIX + p0) = v;
    }
    __syncthreads();

    if (t == 0) out[OUT_IMG + b] = s_flip ? 1.0f : 0.0f;

    float* cur = bufA;
    float* nxt = bufB;

    const int yrow = p0 >> 5;      // all 4 owned px share this row
    const int xcol = p0 & 31;

    // ---- crop-resize (block-uniform branch; y-weights shared over 4 px) ----
    if (do_crop) {
        const int top = s_top, left = s_left;
        float di = fmaxf(((float)yrow + 0.5f) * 0.78125f - 0.5f, 0.0f);
        int i0 = (int)di; float ly = di - (float)i0; int i1 = min(i0 + 1, 24);
        int r0 = (top + i0) * HW, r1 = (top + i1) * HW;
        float omy = 1.0f - ly;
        float oc[3][4];
#pragma unroll
        for (int k = 0; k < 4; ++k) {
            int x = xcol + k;
            float dj = fmaxf(((float)x + 0.5f) * 0.78125f - 0.5f, 0.0f);
            int q0 = (int)dj; float lx = dj - (float)q0; int q1 = min(q0 + 1, 24);
            int c0 = left + q0, c1 = left + q1;
            float w00 = omy * (1.0f - lx), w01 = omy * lx;
            float w10 = ly * (1.0f - lx), w11 = ly * lx;
            int a00 = r0 + c0, a01 = r0 + c1, a10 = r1 + c0, a11 = r1 + c1;
#pragma unroll
            for (int c = 0; c < 3; ++c) {
                const float* p = cur + c * NPIX;
                oc[c][k] = p[a00] * w00 + p[a01] * w01 +
                           p[a10] * w10 + p[a11] * w11;
            }
        }
#pragma unroll
        for (int c = 0; c < 3; ++c)
            *(float4*)(nxt + c * NPIX + p0) =
                make_float4(oc[c][0], oc[c][1], oc[c][2], oc[c][3]);
        float* tp = cur; cur = nxt; nxt = tp;
        __syncthreads();
    }

    // ---- grid sample (flip folded) + folded color chain ----
    {
        const int flip = s_flip, hue = s_hue, grayf = s_gray;
        float K1 = s_bright * s_contr * s_sat;
        float K2 = s_bright - K1;          // br*(1 - ct*sa)
        if (grayf) { K1 = 0.0f; K2 = s_bright; }
        const float th0 = s_theta[0], th1 = s_theta[1], th2 = s_theta[2];
        const float th3 = s_theta[3], th4 = s_theta[4], th5 = s_theta[5];
        float yn = ((float)yrow + 0.5f) * 0.0625f - 1.0f;
        float oc[3][4];
#pragma unroll
        for (int k = 0; k < 4; ++k) {
            int x = xcol + k;
            float xn = ((float)x + 0.5f) * 0.0625f - 1.0f;
            float gx = th0 * xn + th1 * yn + th2;
            float gy = th3 * xn + th4 * yn + th5;
            float ix = reflect32((gx + 1.0f) * 16.0f - 0.5f);
            float iy = reflect32((gy + 1.0f) * 16.0f - 0.5f);
            float fy = floorf(iy), fx = floorf(ix);
            float wy = iy - fy, wx = ix - fx;
            int y0 = min(max((int)fy, 0), 31); int y1 = min(y0 + 1, 31);
            int x0 = min(max((int)fx, 0), 31); int x1 = min(x0 + 1, 31);
            if (flip) { x0 = 31 - x0; x1 = 31 - x1; }
            int r0 = y0 * HW, r1 = y1 * HW;
            float w00 = (1.0f - wy) * (1.0f - wx), w01 = (1.0f - wy) * wx;
            float w10 = wy * (1.0f - wx), w11 = wy * wx;
            int a00 = r0 + x0, a01 = r0 + x1, a10 = r1 + x0, a11 = r1 + x1;
            float ch0 = cur[a00] * w00 + cur[a01] * w01 +
                        cur[a10] * w10 + cur[a11] * w11;
            const float* p1 = cur + NPIX;
            float ch1 = p1[a00] * w00 + p1[a01] * w01 +
                        p1[a10] * w10 + p1[a11] * w11;
            const float* p2 = cur + 2 * NPIX;
            float ch2 = p2[a00] * w00 + p2[a01] * w01 +
                        p2[a10] * w10 + p2[a11] * w11;
            float g = (ch0 + ch1 + ch2) * (1.0f / 3.0f);
            oc[0][k] = K1 * ch0 + K2 * g;
            oc[1][k] = K1 * ch1 + K2 * g;
            oc[2][k] = K1 * ch2 + K2 * g;
        }
        // hue = channel-reversal: swap write targets (block-uniform)
        float* d0 = nxt + (hue ? 2 * NPIX : 0) + p0;
        float* d2 = nxt + (hue ? 0 : 2 * NPIX) + p0;
        *(float4*)d0 = make_float4(oc[0][0], oc[0][1], oc[0][2], oc[0][3]);
        *(float4*)(nxt + NPIX + p0) =
            make_float4(oc[1][0], oc[1][1], oc[1][2], oc[1][3]);
        *(float4*)d2 = make_float4(oc[2][0], oc[2][1], oc[2][2], oc[2][3]);
        float* tp = cur; cur = nxt; nxt = tp;
        __syncthreads();
    }

    // ---- blur (edge-clamped 3x3, row-segment) + solarize + clip + renorm ----
    {
        const int blur = s_blur, solar = s_solar;
        float* o = out + (size_t)b * IMG;
        int ym = max(yrow - 1, 0) * HW, yc = yrow * HW, yp = min(yrow + 1, 31) * HW;
        int xl = max(xcol - 1, 0), xr = min(xcol + 4, 31);
#pragma unroll
        for (int c = 0; c < 3; ++c) {
            const float* p = cur + c * NPIX;
            float4 m0 = *(const float4*)(p + ym + xcol);
            float L0 = p[ym + xl], R0 = p[ym + xr];
            float4 m1 = *(const float4*)(p + yc + xcol);
            float L1 = p[yc + xl], R1 = p[yc + xr];
            float4 m2 = *(const float4*)(p + yp + xcol);
            float L2 = p[yp + xl], R2 = p[yp + xr];
            // horizontal 3-tap sums per row
            float h0x = L0 + m0.x + m0.y, h0y = m0.x + m0.y + m0.z;
            float h0z = m0.y + m0.z + m0.w, h0w = m0.z + m0.w + R0;
            float h1x = L1 + m1.x + m1.y, h1y = m1.x + m1.y + m1.z;
            float h1z = m1.y + m1.z + m1.w, h1w = m1.z + m1.w + R1;
            float h2x = L2 + m2.x + m2.y, h2y = m2.x + m2.y + m2.z;
            float h2z = m2.y + m2.z + m2.w, h2w = m2.z + m2.w + R2;
            float sx = h0x + h1x + h2x, sy = h0y + h1y + h2y;
            float sz = h0z + h1z + h2z, sw = h0w + h1w + h2w;
            float4 r;
            r.x = blur ? sx * (1.0f / 9.0f) : m1.x;
            r.y = blur ? sy * (1.0f / 9.0f) : m1.y;
            r.z = blur ? sz * (1.0f / 9.0f) : m1.z;
            r.w = blur ? sw * (1.0f / 9.0f) : m1.w;
            if (solar) {
                r.x = (r.x > 0.5f) ? 1.0f - r.x : r.x;
                r.y = (r.y > 0.5f) ? 1.0f - r.y : r.y;
                r.z = (r.z > 0.5f) ? 1.0f - r.z : r.z;
                r.w = (r.w > 0.5f) ? 1.0f - r.w : r.w;
            }
            r.x = (fminf(fmaxf(r.x, 0.0f), 1.0f) - MEANc[c]) * INVSTD[c];
            r.y = (fminf(fmaxf(r.y, 0.0f), 1.0f) - MEANc[c]) * INVSTD[c];
            r.z = (fminf(fmaxf(r.z, 0.0f), 1.0f) - MEANc[c]) * INVSTD[c];
            r.w = (fminf(fmaxf(r.w, 0.0f), 1.0f) - MEANc[c]) * INVSTD[c];
            *(float4*)(o + c * NPIX + p0) = r;
        }
    }
}

extern "C" void kernel_launch(void* const* d_in, const int* in_sizes, int n_in,
                              void* d_out, int out_size, void* d_ws, size_t ws_size,
                              hipStream_t stream) {
    const float* x = (const float*)d_in[0];
    const float* aff = (const float*)d_in[1];
    const int* ac = (const int*)d_in[2];
    float* out = (float*)d_out;
    int B = in_sizes[0] / IMG;
    aug_kernel<<<dim3(B), dim3(256), 0, stream>>>(x, aff, ac, out, B);
}

// Round 4
// 194.591 us; speedup vs baseline: 1.0082x; 1.0082x over previous
//
#include <hip/hip_runtime.h>

#define HW 32
#define NPIX 1024      // 32*32
#define IMG 3072       // 3*32*32

// ---------------- threefry2x32 (JAX partitionable semantics) ----------------
__device__ __forceinline__ unsigned rotl32(unsigned x, int d) {
    return (x << d) | (x >> (32 - d));
}

struct UPair { unsigned a, b; };

__device__ __forceinline__ UPair threefry2x32(unsigned k0, unsigned k1,
                                              unsigned x0, unsigned x1) {
    unsigned k2 = k0 ^ k1 ^ 0x1BD11BDAu;
    x0 += k0; x1 += k1;
#define RND(r) { x0 += x1; x1 = rotl32(x1, (r)); x1 ^= x0; }
    RND(13) RND(15) RND(26) RND(6)
    x0 += k1; x1 += k2 + 1u;
    RND(17) RND(29) RND(16) RND(24)
    x0 += k2; x1 += k0 + 2u;
    RND(13) RND(15) RND(26) RND(6)
    x0 += k0; x1 += k1 + 3u;
    RND(17) RND(29) RND(16) RND(24)
    x0 += k1; x1 += k2 + 4u;
    RND(13) RND(15) RND(26) RND(6)
    x0 += k2; x1 += k0 + 5u;
#undef RND
    return {x0, x1};
}

__device__ __forceinline__ float bits_to_u01(unsigned bits) {
    return __uint_as_float((bits >> 9) | 0x3f800000u) - 1.0f;
}

// reference _reflect, lo=-0.5 span=32, manual fmod (t small & positive)
__device__ __forceinline__ float reflect32(float c) {
    float t = fabsf(c + 0.5f);
    float f = floorf(t * 0.03125f);
    float extra = t - 32.0f * f;
    float par = f - 2.0f * floorf(f * 0.5f);   // 0 or 1
    float o = (par == 0.0f) ? (extra - 0.5f) : (31.5f - extra);
    return fminf(fmaxf(o, 0.0f), 31.0f);
}

__global__ __launch_bounds__(256) void aug_kernel(
    const float* __restrict__ xin, const float* __restrict__ aff,
    const int* __restrict__ apply_crop, float* __restrict__ out, int B) {
    // AoS pixel layout: px p lives at buf[4p..4p+3] = {c0,c1,c2,pad}
    __shared__ __align__(16) float bufA[NPIX * 4];
    __shared__ __align__(16) float bufB[NPIX * 4];
    __shared__ float s_theta[6];
    __shared__ int s_top, s_left, s_flip, s_hue, s_gray, s_blur, s_solar;
    __shared__ float s_bright, s_contr, s_sat;

    const int b = blockIdx.x;
    const int t = threadIdx.x;
    const bool do_crop = (apply_crop[0] != 0);

    const int x = t & 31;        // column is FIXED per thread (lane-stride-1)
    const int ybase = t >> 5;    // row = ybase + 8*m

    const float MEANc[3] = {0.5071f, 0.4867f, 0.4408f};
    const float STDc[3]  = {0.2675f, 0.2565f, 0.2761f};
    const float INVSTD[3] = {1.0f / 0.2675f, 1.0f / 0.2565f, 1.0f / 0.2761f};

    // ---- global loads: scalar stride-1 (coalesced), 3 channels x 4 px ----
    const float* imgp = xin + (size_t)b * IMG;
    float l0[4], l1[4], l2[4];
#pragma unroll
    for (int m = 0; m < 4; ++m) {
        int s = t + 256 * m;
        l0[m] = imgp[s];
        l1[m] = imgp[NPIX + s];
        l2[m] = imgp[2 * NPIX + s];
    }

    const size_t OUT_IMG = (size_t)B * IMG;
    if (t < 6) {  // theta into LDS + affine passthrough
        float v = aff[b * 6 + t];
        s_theta[t] = v;
        out[OUT_IMG + (size_t)B + (size_t)b * 6 + t] = v;
    }

    // ---- per-image RNG (jax_threefry_partitionable=True) ----
    if (t < 10) {
        int k = t;
        UPair K = threefry2x32(0u, 42u, 0u, (unsigned)k);  // ks[k]
        if (k < 2) {
            UPair k2 = threefry2x32(K.a, K.b, 0u, 1u);
            UPair r = threefry2x32(k2.a, k2.b, 0u, (unsigned)b);
            int val = (int)((r.a ^ r.b) & 7u);
            if (k == 0) s_top = val; else s_left = val;
        } else {
            UPair r = threefry2x32(K.a, K.b, 0u, (unsigned)b);
            float u = bits_to_u01(r.a ^ r.b);
            if      (k == 2) s_flip  = (u < 0.5f);
            else if (k == 3) s_bright = 1.0f + (u - 0.5f) * 0.8f;
            else if (k == 4) s_contr  = 1.0f + (u - 0.5f) * 0.8f;
            else if (k == 5) s_sat    = 1.0f + (u - 0.5f) * 0.8f;
            else if (k == 6) s_hue   = (u < 0.5f);
            else if (k == 7) s_gray  = (u < 0.2f);
            else if (k == 8) s_blur  = (u < 0.5f);
            else             s_solar = (u < 0.1f);
        }
    }

    // ---- denormalize + stage AoS (b128 writes, lane-stride-1) ----
#pragma unroll
    for (int m = 0; m < 4; ++m) {
        int s = t + 256 * m;
        *(float4*)(bufA + 4 * s) = make_float4(
            l0[m] * STDc[0] + MEANc[0],
            l1[m] * STDc[1] + MEANc[1],
            l2[m] * STDc[2] + MEANc[2], 0.0f);
    }
    __syncthreads();

    if (t == 0) out[OUT_IMG + b] = s_flip ? 1.0f : 0.0f;

    float* cur = bufA;
    float* nxt = bufB;

    // ---- crop-resize (block-uniform; x-side weights hoisted) ----
    if (do_crop) {
        const int top = s_top, left = s_left;
        float dj = fmaxf(((float)x + 0.5f) * 0.78125f - 0.5f, 0.0f);
        int q0 = (int)dj; float lx = dj - (float)q0; int q1 = min(q0 + 1, 24);
        int c0 = left + q0, c1 = left + q1;
        float omx = 1.0f - lx;
#pragma unroll
        for (int m = 0; m < 4; ++m) {
            int y = ybase + 8 * m;
            int s = y * HW + x;
            float di = fmaxf(((float)y + 0.5f) * 0.78125f - 0.5f, 0.0f);
            int i0 = (int)di; float ly = di - (float)i0; int i1 = min(i0 + 1, 24);
            int r0 = (top + i0) * HW, r1 = (top + i1) * HW;
            float w00 = (1.0f - ly) * omx, w01 = (1.0f - ly) * lx;
            float w10 = ly * omx, w11 = ly * lx;
            float4 v00 = *(const float4*)(cur + 4 * (r0 + c0));
            float4 v01 = *(const float4*)(cur + 4 * (r0 + c1));
            float4 v10 = *(const float4*)(cur + 4 * (r1 + c0));
            float4 v11 = *(const float4*)(cur + 4 * (r1 + c1));
            float4 r;
            r.x = v00.x * w00 + v01.x * w01 + v10.x * w10 + v11.x * w11;
            r.y = v00.y * w00 + v01.y * w01 + v10.y * w10 + v11.y * w11;
            r.z = v00.z * w00 + v01.z * w01 + v10.z * w10 + v11.z * w11;
            r.w = 0.0f;
            *(float4*)(nxt + 4 * s) = r;
        }
        float* tp = cur; cur = nxt; nxt = tp;
        __syncthreads();
    }

    // ---- grid sample (flip folded) + folded color chain; keep own px ----
    float4 own[4];
    {
        const int flip = s_flip, hue = s_hue, grayf = s_gray;
        float K1 = s_bright * s_contr * s_sat;
        float K2 = s_bright - K1;          // br*(1 - ct*sa)
        if (grayf) { K1 = 0.0f; K2 = s_bright; }
        const float th0 = s_theta[0], th1 = s_theta[1], th2 = s_theta[2];
        const float th3 = s_theta[3], th4 = s_theta[4], th5 = s_theta[5];
        const float xn = ((float)x + 0.5f) * 0.0625f - 1.0f;
        const float gx0 = th0 * xn + th2;   // x-terms hoisted
        const float gy0 = th3 * xn + th5;
#pragma unroll
        for (int m = 0; m < 4; ++m) {
            int y = ybase + 8 * m;
            int s = y * HW + x;
            float yn = ((float)y + 0.5f) * 0.0625f - 1.0f;
            float gx = gx0 + th1 * yn;
            float gy = gy0 + th4 * yn;
            float ix = reflect32((gx + 1.0f) * 16.0f - 0.5f);
            float iy = reflect32((gy + 1.0f) * 16.0f - 0.5f);
            float fy = floorf(iy), fx = floorf(ix);
            float wy = iy - fy, wx = ix - fx;
            int y0 = min(max((int)fy, 0), 31); int y1 = min(y0 + 1, 31);
            int x0 = min(max((int)fx, 0), 31); int x1 = min(x0 + 1, 31);
            if (flip) { x0 = 31 - x0; x1 = 31 - x1; }
            int r0 = y0 * HW, r1 = y1 * HW;
            float w00 = (1.0f - wy) * (1.0f - wx), w01 = (1.0f - wy) * wx;
            float w10 = wy * (1.0f - wx), w11 = wy * wx;
            float4 v00 = *(const float4*)(cur + 4 * (r0 + x0));
            float4 v01 = *(const float4*)(cur + 4 * (r0 + x1));
            float4 v10 = *(const float4*)(cur + 4 * (r1 + x0));
            float4 v11 = *(const float4*)(cur + 4 * (r1 + x1));
            float ch0 = v00.x * w00 + v01.x * w01 + v10.x * w10 + v11.x * w11;
            float ch1 = v00.y * w00 + v01.y * w01 + v10.y * w10 + v11.y * w11;
            float ch2 = v00.z * w00 + v01.z * w01 + v10.z * w10 + v11.z * w11;
            float g = (ch0 + ch1 + ch2) * (1.0f / 3.0f);
            float o0 = K1 * ch0 + K2 * g;
            float o1 = K1 * ch1 + K2 * g;
            float o2 = K1 * ch2 + K2 * g;
            if (hue) { float tmp = o0; o0 = o2; o2 = tmp; }   // channel reverse
            float4 r = make_float4(o0, o1, o2, 0.0f);
            own[m] = r;
        }
        // defer the LDS writes until after all reads of `cur` are done
        float* tp = cur; cur = nxt; nxt = tp;   // cur = gs output buffer
#pragma unroll
        for (int m = 0; m < 4; ++m) {
            int s = (ybase + 8 * m) * HW + x;
            *(float4*)(cur + 4 * s) = own[m];
        }
        __syncthreads();
    }

    // ---- blur horizontal pass: h = left + center + right (edge-clamped) ----
    float4 hsum[4];
    {
        const int xl = max(x - 1, 0), xr = min(x + 1, 31);
#pragma unroll
        for (int m = 0; m < 4; ++m) {
            int row = (ybase + 8 * m) * HW;
            float4 vl = *(const float4*)(cur + 4 * (row + xl));
            float4 vr = *(const float4*)(cur + 4 * (row + xr));
            float4 h;
            h.x = vl.x + own[m].x + vr.x;
            h.y = vl.y + own[m].y + vr.y;
            h.z = vl.z + own[m].z + vr.z;
            h.w = 0.0f;
            hsum[m] = h;
        }
        // h goes into the other buffer
#pragma unroll
        for (int m = 0; m < 4; ++m) {
            int s = (ybase + 8 * m) * HW + x;
            *(float4*)(nxt + 4 * s) = hsum[m];
        }
        __syncthreads();
    }

    // ---- blur vertical + solarize + clip + renorm + store ----
    {
        const int blur = s_blur, solar = s_solar;
        float* o = out + (size_t)b * IMG;
        const float* hb = nxt;
#pragma unroll
        for (int m = 0; m < 4; ++m) {
            int y = ybase + 8 * m;
            int s = y * HW + x;
            int ym = max(y - 1, 0) * HW + x, yp = min(y + 1, 31) * HW + x;
            float4 hu = *(const float4*)(hb + 4 * ym);
            float4 hd = *(const float4*)(hb + 4 * yp);
            float r0 = blur ? (hu.x + hsum[m].x + hd.x) * (1.0f / 9.0f) : own[m].x;
            float r1 = blur ? (hu.y + hsum[m].y + hd.y) * (1.0f / 9.0f) : own[m].y;
            float r2 = blur ? (hu.z + hsum[m].z + hd.z) * (1.0f / 9.0f) : own[m].z;
            if (solar) {
                r0 = (r0 > 0.5f) ? 1.0f - r0 : r0;
                r1 = (r1 > 0.5f) ? 1.0f - r1 : r1;
                r2 = (r2 > 0.5f) ? 1.0f - r2 : r2;
            }
            r0 = (fminf(fmaxf(r0, 0.0f), 1.0f) - MEANc[0]) * INVSTD[0];
            r1 = (fminf(fmaxf(r1, 0.0f), 1.0f) - MEANc[1]) * INVSTD[1];
            r2 = (fminf(fmaxf(r2, 0.0f), 1.0f) - MEANc[2]) * INVSTD[2];
            o[s] = r0;
            o[NPIX + s] = r1;
            o[2 * NPIX + s] = r2;
        }
    }
}

extern "C" void kernel_launch(void* const* d_in, const int* in_sizes, int n_in,
                              void* d_out, int out_size, void* d_ws, size_t ws_size,
                              hipStream_t stream) {
    const float* x = (const float*)d_in[0];
    const float* aff = (const float*)d_in[1];
    const int* ac = (const int*)d_in[2];
    float* out = (float*)d_out;
    int B = in_sizes[0] / IMG;
    aug_kernel<<<dim3(B), dim3(256), 0, stream>>>(x, aff, ac, out, B);
}